// Round 8
// baseline (1702.573 us; speedup 1.0000x reference)
//
#include <hip/hip_runtime.h>
#include <hip/hip_fp16.h>
#include <math.h>

#define N_NODES 500000
#define N_EDGES 4000000
#define FDIM 10   // IN_DIM + HID
#define HID 8

// Dest space: interleaved, dest = 2*col (mi side) or 2*row+1 (mo side).
#define DSPACE (2 * N_NODES)
#define NB 512
#define BSHIFT 11
#define BMASK 2047
#define NB_USED ((DSPACE + BMASK) / 2048)   // 489

#define IN_BLOCKS ((N_NODES + 255) / 256)       // 1954
#define ROWS_PAD (IN_BLOCKS * 256)              // 500224
#define NPH 4                                   // source-range phases
#define PHB 17                                  // phase = src >> 17

// packed fp16 pair
typedef _Float16 h2v __attribute__((ext_vector_type(2)));

__device__ __forceinline__ h2v u2h(unsigned x) {
    union { unsigned u; h2v h; } t; t.u = x; return t.h;
}
__device__ __forceinline__ unsigned packh2(float a, float b) {
    union { __half2 h; unsigned u; } t; t.h = __floats2half2_rn(a, b); return t.u;
}
__device__ __forceinline__ float rfl_f(float x) {
    return __int_as_float(__builtin_amdgcn_readfirstlane(__float_as_int(x)));
}

// Non-temporal loads for single-use streams (index arrays, entries):
// keeps them from evicting gather-resident node-table lines in L2.
__device__ __forceinline__ int nt_ld_i(const int* p) { return __builtin_nontemporal_load(p); }
__device__ __forceinline__ unsigned nt_ld_u(const unsigned* p) { return __builtin_nontemporal_load(p); }

// ---------------------------------------------------------------------------
// Fast transcendentals (hw exp2/rcp; error ~1e-6 vs threshold 1.35e-2)
// ---------------------------------------------------------------------------
__device__ __forceinline__ float fast_tanh(float x) {
    float e = __builtin_amdgcn_exp2f(x * 2.885390082f);  // exp(2x)
    return 1.0f - 2.0f * __builtin_amdgcn_rcpf(e + 1.0f);
}
__device__ __forceinline__ float fast_sigmoid(float x) {
    float e = __builtin_amdgcn_exp2f(-1.442695041f * x); // exp(-x)
    return __builtin_amdgcn_rcpf(1.0f + e);
}

// Edge MLP second half: acc = base + W_other^T * other_row; return sigmoid(e2).
__device__ __forceinline__ float edge_sig(const uint4* __restrict__ wq,
                                          const float* base,
                                          const unsigned* cp,
                                          const float* sv, float sc) {
    float acc[HID];
#pragma unroll
    for (int j = 0; j < HID; j++) acc[j] = base[j];
#pragma unroll
    for (int kk = 0; kk < 5; kk++) {
        uint4 wa = wq[2 * kk];
        uint4 wb = wq[2 * kk + 1];
        h2v a = u2h(cp[kk]);
        acc[0] = __builtin_amdgcn_fdot2(a, u2h(wa.x), acc[0], false);
        acc[1] = __builtin_amdgcn_fdot2(a, u2h(wa.y), acc[1], false);
        acc[2] = __builtin_amdgcn_fdot2(a, u2h(wa.z), acc[2], false);
        acc[3] = __builtin_amdgcn_fdot2(a, u2h(wa.w), acc[3], false);
        acc[4] = __builtin_amdgcn_fdot2(a, u2h(wb.x), acc[4], false);
        acc[5] = __builtin_amdgcn_fdot2(a, u2h(wb.y), acc[5], false);
        acc[6] = __builtin_amdgcn_fdot2(a, u2h(wb.z), acc[6], false);
        acc[7] = __builtin_amdgcn_fdot2(a, u2h(wb.w), acc[7], false);
    }
    float d = sc;
#pragma unroll
    for (int j = 0; j < HID; j++) d += fast_tanh(acc[j]) * sv[j];
    return fast_sigmoid(d);
}

// ---------------------------------------------------------------------------
// Input network: H table (fp16, 16 B rows) + static X table (fp16, 4 B rows).
// ---------------------------------------------------------------------------
__global__ __launch_bounds__(256) void input_kernel(const float* __restrict__ x,
                                                    const float* __restrict__ win_w,
                                                    const float* __restrict__ win_b,
                                                    uint4* __restrict__ xh,
                                                    unsigned* __restrict__ xs) {
    int n = blockIdx.x * 256 + threadIdx.x;   // grid covers ROWS_PAD exactly
    float x0 = 0.f, x1 = 0.f;
    if (n < N_NODES) { x0 = x[2 * n]; x1 = x[2 * n + 1]; }
    float h[HID];
#pragma unroll
    for (int j = 0; j < HID; j++)
        h[j] = fast_tanh(x0 * win_w[j] + x1 * win_w[HID + j] + win_b[j]);
    xh[n] = make_uint4(packh2(h[0], h[1]), packh2(h[2], h[3]),
                       packh2(h[4], h[5]), packh2(h[6], h[7]));
    xs[n] = packh2(x0, x1);
}

// ---------------------------------------------------------------------------
// K0: bucket histogram, LDS-staged.
// ---------------------------------------------------------------------------
__global__ void bucket_hist_kernel(const int* __restrict__ row,
                                   const int* __restrict__ col,
                                   int* __restrict__ g_cnt) {
    __shared__ int s_cnt[NB];
    int tid = threadIdx.x;
    for (int i = tid; i < NB; i += 256) s_cnt[i] = 0;
    __syncthreads();
    int base = blockIdx.x * 4096;
#pragma unroll
    for (int k = 0; k < 16; k++) {
        int e = base + k * 256 + tid;
        if (e < N_EDGES) {
            int c = nt_ld_i(col + e), r = nt_ld_i(row + e);
            atomicAdd(&s_cnt[(2 * c) >> BSHIFT], 1);
            atomicAdd(&s_cnt[(2 * r + 1) >> BSHIFT], 1);
        }
    }
    __syncthreads();
    for (int i = tid; i < NB; i += 256) {
        int v = s_cnt[i];
        if (v) atomicAdd(&g_cnt[i], v);
    }
}

// ---------------------------------------------------------------------------
// K1: exclusive scan of bucket counts.
// ---------------------------------------------------------------------------
__global__ void bucket_scan_kernel(const int* __restrict__ g_cnt,
                                   int* __restrict__ bucket_base,
                                   int* __restrict__ bucket_cur) {
    __shared__ int s[NB];
    int t = threadIdx.x;
    int c = g_cnt[t];
    s[t] = c;
    __syncthreads();
    for (int off = 1; off < NB; off <<= 1) {
        int v = (t >= off) ? s[t - off] : 0;
        __syncthreads();
        s[t] += v;
        __syncthreads();
    }
    int ex = s[t] - c;
    bucket_base[t] = ex;
    bucket_cur[t] = ex;
    if (t == NB - 1) bucket_base[NB] = s[t];
}

// ---------------------------------------------------------------------------
// K2: binning into bucket-ordered staging (LDS), coalesced flush.
// Items: (dest_local 11 bits << 19) | src 19 bits.
// ---------------------------------------------------------------------------
__global__ void bin_kernel(const int* __restrict__ row,
                           const int* __restrict__ col,
                           int* __restrict__ bucket_cur,
                           unsigned int* __restrict__ binned) {
    __shared__ int s_cnt[NB];
    __shared__ int s_start[NB];
    __shared__ int s_cur[NB];
    __shared__ int s_gbase[NB];
    __shared__ unsigned int s_items[8192];
    __shared__ unsigned short s_ibkt[8192];

    int tid = threadIdx.x;
    if (tid < NB) s_cnt[tid] = 0;
    __syncthreads();

    int base = blockIdx.x * 4096;
    int cc[4], rr[4];
#pragma unroll
    for (int k = 0; k < 4; k++) {
        int e = base + k * 1024 + tid;
        bool ok = (e < N_EDGES);
        cc[k] = ok ? nt_ld_i(col + e) : -1;
        rr[k] = ok ? nt_ld_i(row + e) : -1;
        if (ok) {
            atomicAdd(&s_cnt[(2 * cc[k]) >> BSHIFT], 1);
            atomicAdd(&s_cnt[(2 * rr[k] + 1) >> BSHIFT], 1);
        }
    }
    __syncthreads();

    if (tid < NB) s_start[tid] = s_cnt[tid];
    __syncthreads();
    for (int off = 1; off < NB; off <<= 1) {
        int v = 0;
        if (tid < NB && tid >= off) v = s_start[tid - off];
        __syncthreads();
        if (tid < NB) s_start[tid] += v;
        __syncthreads();
    }
    if (tid < NB) {
        int ex = s_start[tid] - s_cnt[tid];
        s_start[tid] = ex;
        s_cur[tid] = ex;
    }
    __syncthreads();

#pragma unroll
    for (int k = 0; k < 4; k++) {
        if (cc[k] >= 0) {
            int d0 = 2 * cc[k];
            int b0 = d0 >> BSHIFT;
            int s0 = atomicAdd(&s_cur[b0], 1);
            s_items[s0] = ((unsigned)(d0 & BMASK) << 19) | (unsigned)rr[k];
            s_ibkt[s0] = (unsigned short)b0;
            int d1 = 2 * rr[k] + 1;
            int b1 = d1 >> BSHIFT;
            int s1 = atomicAdd(&s_cur[b1], 1);
            s_items[s1] = ((unsigned)(d1 & BMASK) << 19) | (unsigned)cc[k];
            s_ibkt[s1] = (unsigned short)b1;
        }
    }
    __syncthreads();

    if (tid < NB) s_gbase[tid] = atomicAdd(&bucket_cur[tid], s_cnt[tid]);
    __syncthreads();

    int tot = s_start[NB - 1] + s_cnt[NB - 1];
    for (int s = tid; s < tot; s += 1024) {
        int b = s_ibkt[s];
        int g = s_gbase[b] + (s - s_start[b]);
        binned[g] = s_items[s];
    }
}

// ---------------------------------------------------------------------------
// K3: per-bucket phase sort: entries[bucket] = binned[bucket] reordered so
// the 4 source-range phases (src>>PHB) are contiguous. Full items kept.
// offs4[b*4+ph] = start of (b, ph); offs4[(b+1)*4] = end of bucket b.
// ---------------------------------------------------------------------------
__global__ __launch_bounds__(1024) void phase_sort_kernel(
        const unsigned int* __restrict__ binned,
        const int* __restrict__ bucket_base,
        int* __restrict__ offs4,
        unsigned int* __restrict__ entries) {
    __shared__ int s_cnt[NPH];
    __shared__ int s_cur[NPH];
    int t = threadIdx.x;
    int b = blockIdx.x;
    int ebase = bucket_base[b];
    int eend = bucket_base[b + 1];

    if (t < NPH) s_cnt[t] = 0;
    __syncthreads();

    for (int p = ebase + t; p < eend; p += 1024)
        atomicAdd(&s_cnt[(nt_ld_u(binned + p) & 0x7FFFFu) >> PHB], 1);
    __syncthreads();

    if (t == 0) {
        int run = 0;
#pragma unroll
        for (int ph = 0; ph < NPH; ph++) {
            s_cur[ph] = run;
            offs4[b * NPH + ph] = ebase + run;
            run += s_cnt[ph];
        }
        if (b == 0) offs4[NB_USED * NPH] = 2 * N_EDGES;
    }
    __syncthreads();

    for (int p = ebase + t; p < eend; p += 1024) {
        unsigned it = nt_ld_u(binned + p);
        int pos = atomicAdd(&s_cur[(it & 0x7FFFFu) >> PHB], 1);
        entries[ebase + pos] = it;
    }
}

// ---------------------------------------------------------------------------
// Fused gather + edge-MLP + node network, BUCKET-LDS form.
//   One block (1024 thr) per 2048-dest bucket:
//   - per-node self-dots (us top / vs bottom, bias folded) in s_sd (64 KB)
//   - messages accumulate in s_m[2048][10] via LDS atomics (80 KB)
//   - entries consumed BLOCK-STRIDED (balanced: ~4/thread/phase), paired
//     2-at-a-time so 2 independent row-gathers are in flight per lane
//   - per-phase __syncthreads keeps the chip on one ~2.6 MB source slice
//   - node-net epilogue straight out of LDS, coalesced xh_next write
// ---------------------------------------------------------------------------
__global__ __launch_bounds__(1024, 1) void node_kernel(
        const uint4* __restrict__ xh,
        const unsigned* __restrict__ xs,
        const int* __restrict__ offs4,
        const unsigned int* __restrict__ entries,
        const float* __restrict__ e1_w,
        const float* __restrict__ e1_b,
        const float* __restrict__ e2_w,
        const float* __restrict__ e2_b,
        const float* __restrict__ n1_w,
        const float* __restrict__ n1_b,
        const float* __restrict__ n2_w,
        const float* __restrict__ n2_b,
        uint4* __restrict__ xh_next) {
    __shared__ uint4 s_e4[20];          // e1_w packed h2: rows 0..9 top, 10..19 bottom
    __shared__ float s_scal[17];        // e1b[8], e2w[8], e2b
    __shared__ float s_n1w[30 * HID];
    __shared__ float s_n1b[HID];
    __shared__ float s_n2w[HID * HID];
    __shared__ float s_n2b[HID];
    __shared__ float s_sd[1024 * 16];   // per-node us[8] | vs[8]      (64 KB)
    __shared__ float s_m[2048 * 10];    // per-dest message accum      (80 KB)

    int t = threadIdx.x;
    int b = blockIdx.x;

    if (t < 80) {
        int kk = t >> 3, j = t & 7;
        ((unsigned*)s_e4)[t] = packh2(e1_w[(2 * kk) * HID + j],
                                      e1_w[(2 * kk + 1) * HID + j]);
    } else if (t < 88) s_scal[t - 80] = e1_b[t - 80];
    else if (t < 96) s_scal[t - 80] = e2_w[t - 88];
    else if (t == 96) s_scal[16] = e2_b[0];
    else if (t >= 128 && t < 368) s_n1w[t - 128] = n1_w[t - 128];
    else if (t >= 368 && t < 376) s_n1b[t - 368] = n1_b[t - 368];
    else if (t >= 376 && t < 440) s_n2w[t - 376] = n2_w[t - 376];
    else if (t >= 440 && t < 448) s_n2b[t - 440] = n2_b[t - 440];

    for (int i = t; i < 2048 * 10; i += 1024) s_m[i] = 0.f;
    __syncthreads();

    // wave-uniform scalars -> SGPRs
    float sb[HID], sv[HID];
#pragma unroll
    for (int j = 0; j < HID; j++) { sb[j] = rfl_f(s_scal[j]); sv[j] = rfl_f(s_scal[8 + j]); }
    float sc = rfl_f(s_scal[16]);

    // --- prologue: per-node self-dots (both sides) ---
    int n0 = b * 1024 + t;
    {
        uint4 xq = make_uint4(0, 0, 0, 0); unsigned xx = 0;
        if (n0 < N_NODES) { xq = xh[n0]; xx = xs[n0]; }
        unsigned xp[5] = { xq.x, xq.y, xq.z, xq.w, xx };
        float us[HID], vs[HID];
#pragma unroll
        for (int j = 0; j < HID; j++) { us[j] = sb[j]; vs[j] = sb[j]; }
#pragma unroll
        for (int kk = 0; kk < 5; kk++) {
            h2v a = u2h(xp[kk]);
            uint4 wa = s_e4[2 * kk],      wb = s_e4[2 * kk + 1];       // top
            uint4 wc = s_e4[10 + 2 * kk], wd = s_e4[11 + 2 * kk];      // bottom
            us[0] = __builtin_amdgcn_fdot2(a, u2h(wa.x), us[0], false);
            us[1] = __builtin_amdgcn_fdot2(a, u2h(wa.y), us[1], false);
            us[2] = __builtin_amdgcn_fdot2(a, u2h(wa.z), us[2], false);
            us[3] = __builtin_amdgcn_fdot2(a, u2h(wa.w), us[3], false);
            us[4] = __builtin_amdgcn_fdot2(a, u2h(wb.x), us[4], false);
            us[5] = __builtin_amdgcn_fdot2(a, u2h(wb.y), us[5], false);
            us[6] = __builtin_amdgcn_fdot2(a, u2h(wb.z), us[6], false);
            us[7] = __builtin_amdgcn_fdot2(a, u2h(wb.w), us[7], false);
            vs[0] = __builtin_amdgcn_fdot2(a, u2h(wc.x), vs[0], false);
            vs[1] = __builtin_amdgcn_fdot2(a, u2h(wc.y), vs[1], false);
            vs[2] = __builtin_amdgcn_fdot2(a, u2h(wc.z), vs[2], false);
            vs[3] = __builtin_amdgcn_fdot2(a, u2h(wc.w), vs[3], false);
            vs[4] = __builtin_amdgcn_fdot2(a, u2h(wd.x), vs[4], false);
            vs[5] = __builtin_amdgcn_fdot2(a, u2h(wd.y), vs[5], false);
            vs[6] = __builtin_amdgcn_fdot2(a, u2h(wd.z), vs[6], false);
            vs[7] = __builtin_amdgcn_fdot2(a, u2h(wd.w), vs[7], false);
        }
        float4* sd = (float4*)(s_sd + t * 16);
        sd[0] = make_float4(us[0], us[1], us[2], us[3]);
        sd[1] = make_float4(us[4], us[5], us[6], us[7]);
        sd[2] = make_float4(vs[0], vs[1], vs[2], vs[3]);
        sd[3] = make_float4(vs[4], vs[5], vs[6], vs[7]);
    }
    __syncthreads();

    // --- phase-swept gather + edge MLP + LDS accumulate ---
    for (int ph = 0; ph < NPH; ph++) {
        int ps = offs4[b * NPH + ph];
        int pe = offs4[b * NPH + ph + 1];
        for (int p = ps + t; p < pe; p += 2048) {
            int pB = p + 1024;
            bool vB = pB < pe;
            // pair of entries: both gathers issue before either compute
            unsigned itA = nt_ld_u(entries + p);
            unsigned itB = vB ? nt_ld_u(entries + pB) : itA;
            int srcA = itA & 0x7FFFF, srcB = itB & 0x7FFFF;
            uint4 HA = xh[srcA]; unsigned XA = xs[srcA];
            uint4 HB = xh[srcB]; unsigned XB = xs[srcB];

            {
                int dl = itA >> 19;
                const float4* bp = (const float4*)(s_sd + (dl >> 1) * 16 + (dl & 1) * 8);
                float4 b0 = bp[0], b1 = bp[1];
                float base[HID] = { b0.x, b0.y, b0.z, b0.w, b1.x, b1.y, b1.z, b1.w };
                const uint4* wq = (dl & 1) ? s_e4 : s_e4 + 10;
                unsigned cp[5] = { HA.x, HA.y, HA.z, HA.w, XA };
                float e = edge_sig(wq, base, cp, sv, sc);
                float* md = s_m + dl * 10;
#pragma unroll
                for (int kk = 0; kk < 5; kk++) {
                    h2v a = u2h(cp[kk]);
                    atomicAdd(md + 2 * kk,     e * (float)a.x);
                    atomicAdd(md + 2 * kk + 1, e * (float)a.y);
                }
            }
            if (vB) {
                int dl = itB >> 19;
                const float4* bp = (const float4*)(s_sd + (dl >> 1) * 16 + (dl & 1) * 8);
                float4 b0 = bp[0], b1 = bp[1];
                float base[HID] = { b0.x, b0.y, b0.z, b0.w, b1.x, b1.y, b1.z, b1.w };
                const uint4* wq = (dl & 1) ? s_e4 : s_e4 + 10;
                unsigned cp[5] = { HB.x, HB.y, HB.z, HB.w, XB };
                float e = edge_sig(wq, base, cp, sv, sc);
                float* md = s_m + dl * 10;
#pragma unroll
                for (int kk = 0; kk < 5; kk++) {
                    h2v a = u2h(cp[kk]);
                    atomicAdd(md + 2 * kk,     e * (float)a.x);
                    atomicAdd(md + 2 * kk + 1, e * (float)a.y);
                }
            }
        }
        __syncthreads();
    }

    // --- node-net epilogue straight out of LDS ---
    if (n0 < N_NODES) {
        uint4 xq = xh[n0]; unsigned xx = xs[n0];
        unsigned xp[5] = { xq.x, xq.y, xq.z, xq.w, xx };
        float xn[FDIM];
#pragma unroll
        for (int kk = 0; kk < 5; kk++) {
            h2v a = u2h(xp[kk]);
            xn[2 * kk] = (float)a.x; xn[2 * kk + 1] = (float)a.y;
        }
        const float* mi = s_m + (2 * t) * 10;
        const float* mo = s_m + (2 * t + 1) * 10;
        float h1[HID];
#pragma unroll
        for (int j = 0; j < HID; j++) h1[j] = s_n1b[j];
#pragma unroll
        for (int k = 0; k < FDIM; k++) {
            float mik = mi[k], mok = mo[k];
#pragma unroll
            for (int j = 0; j < HID; j++) {
                h1[j] += mik * s_n1w[k * HID + j];
                h1[j] += mok * s_n1w[(FDIM + k) * HID + j];
                h1[j] += xn[k] * s_n1w[(2 * FDIM + k) * HID + j];
            }
        }
#pragma unroll
        for (int j = 0; j < HID; j++) h1[j] = fast_tanh(h1[j]);

        float H[HID];
#pragma unroll
        for (int j = 0; j < HID; j++) H[j] = s_n2b[j];
#pragma unroll
        for (int k = 0; k < HID; k++) {
#pragma unroll
            for (int j = 0; j < HID; j++) H[j] += h1[k] * s_n2w[k * HID + j];
        }
        xh_next[n0] = make_uint4(packh2(fast_tanh(H[0]), fast_tanh(H[1])),
                                 packh2(fast_tanh(H[2]), fast_tanh(H[3])),
                                 packh2(fast_tanh(H[4]), fast_tanh(H[5])),
                                 packh2(fast_tanh(H[6]), fast_tanh(H[7])));
    }
}

// ---------------------------------------------------------------------------
// Final edge network -> out. Weights packed-h2 (LDS + SGPR), dots via
// v_dot2_f32_f16. Index streams non-temporal.
// ---------------------------------------------------------------------------
__global__ __launch_bounds__(256) void edge_kernel(const int* __restrict__ row,
                                                   const int* __restrict__ col,
                                                   const uint4* __restrict__ xh,
                                                   const unsigned* __restrict__ xs,
                                                   const float* __restrict__ e1_w,
                                                   const float* __restrict__ e1_b,
                                                   const float* __restrict__ e2_w,
                                                   const float* __restrict__ e2_b,
                                                   float* __restrict__ out) {
    __shared__ uint4 s_e4[20];
    __shared__ float s_scal[17];
    int tid = threadIdx.x;
    if (tid < 80) {
        int kk = tid >> 3, j = tid & 7;
        ((unsigned*)s_e4)[tid] = packh2(e1_w[(2 * kk) * HID + j],
                                        e1_w[(2 * kk + 1) * HID + j]);
    } else if (tid < 88) s_scal[tid - 80] = e1_b[tid - 80];
    else if (tid < 96) s_scal[tid - 80] = e2_w[tid - 88];
    else if (tid == 96) s_scal[16] = e2_b[0];
    __syncthreads();

    float sb[HID], sv[HID];
#pragma unroll
    for (int j = 0; j < HID; j++) { sb[j] = rfl_f(s_scal[j]); sv[j] = rfl_f(s_scal[8 + j]); }
    float sc = rfl_f(s_scal[16]);

    int i = blockIdx.x * 256 + tid;
    if (i >= N_EDGES) return;

    int r = nt_ld_i(row + i), c = nt_ld_i(col + i);
    uint4 aq = xh[c]; unsigned ax = xs[c];
    uint4 bq = xh[r]; unsigned bx = xs[r];
    unsigned ap[5] = { aq.x, aq.y, aq.z, aq.w, ax };
    unsigned bp[5] = { bq.x, bq.y, bq.z, bq.w, bx };

    float acc[HID];
#pragma unroll
    for (int j = 0; j < HID; j++) acc[j] = sb[j];
#pragma unroll
    for (int kk = 0; kk < 5; kk++) {
        uint4 wa = s_e4[2 * kk], wb = s_e4[2 * kk + 1];
        h2v a = u2h(ap[kk]);
        acc[0] = __builtin_amdgcn_fdot2(a, u2h(wa.x), acc[0], false);
        acc[1] = __builtin_amdgcn_fdot2(a, u2h(wa.y), acc[1], false);
        acc[2] = __builtin_amdgcn_fdot2(a, u2h(wa.z), acc[2], false);
        acc[3] = __builtin_amdgcn_fdot2(a, u2h(wa.w), acc[3], false);
        acc[4] = __builtin_amdgcn_fdot2(a, u2h(wb.x), acc[4], false);
        acc[5] = __builtin_amdgcn_fdot2(a, u2h(wb.y), acc[5], false);
        acc[6] = __builtin_amdgcn_fdot2(a, u2h(wb.z), acc[6], false);
        acc[7] = __builtin_amdgcn_fdot2(a, u2h(wb.w), acc[7], false);
    }
#pragma unroll
    for (int kk = 0; kk < 5; kk++) {
        uint4 wa = s_e4[10 + 2 * kk], wb = s_e4[11 + 2 * kk];
        h2v b = u2h(bp[kk]);
        acc[0] = __builtin_amdgcn_fdot2(b, u2h(wa.x), acc[0], false);
        acc[1] = __builtin_amdgcn_fdot2(b, u2h(wa.y), acc[1], false);
        acc[2] = __builtin_amdgcn_fdot2(b, u2h(wa.z), acc[2], false);
        acc[3] = __builtin_amdgcn_fdot2(b, u2h(wa.w), acc[3], false);
        acc[4] = __builtin_amdgcn_fdot2(b, u2h(wb.x), acc[4], false);
        acc[5] = __builtin_amdgcn_fdot2(b, u2h(wb.y), acc[5], false);
        acc[6] = __builtin_amdgcn_fdot2(b, u2h(wb.z), acc[6], false);
        acc[7] = __builtin_amdgcn_fdot2(b, u2h(wb.w), acc[7], false);
    }

    float d = sc;
#pragma unroll
    for (int j = 0; j < HID; j++) d += fast_tanh(acc[j]) * sv[j];
    out[i] = fast_sigmoid(d);
}

// ---------------------------------------------------------------------------
extern "C" void kernel_launch(void* const* d_in, const int* in_sizes, int n_in,
                              void* d_out, int out_size, void* d_ws, size_t ws_size,
                              hipStream_t stream) {
    const float* x      = (const float*)d_in[0];
    const int*   eidx   = (const int*)d_in[1];
    const float* win_w  = (const float*)d_in[2];
    const float* win_b  = (const float*)d_in[3];
    const float* e1_w   = (const float*)d_in[4];
    const float* e1_b   = (const float*)d_in[5];
    const float* e2_w   = (const float*)d_in[6];
    const float* e2_b   = (const float*)d_in[7];
    const float* n1_w   = (const float*)d_in[8];
    const float* n1_b   = (const float*)d_in[9];
    const float* n2_w   = (const float*)d_in[10];
    const float* n2_b   = (const float*)d_in[11];
    float* out = (float*)d_out;

    const int* row = eidx;
    const int* col = eidx + N_EDGES;

    // Workspace layout (~82 MB):
    char* w = (char*)d_ws;
    uint4* xh0 = (uint4*)w;            w += (size_t)ROWS_PAD * 16;   // 8 MB
    uint4* xh1 = (uint4*)w;            w += (size_t)ROWS_PAD * 16;   // 8 MB
    unsigned* xs = (unsigned*)w;       w += (size_t)ROWS_PAD * 4;    // 2 MB
    unsigned int* binned = (unsigned int*)w; w += (size_t)2 * N_EDGES * 4;  // 32 MB
    unsigned int* entries = (unsigned int*)w; w += (size_t)2 * N_EDGES * 4; // 32 MB
    int* offs4 = (int*)w;              w += ((size_t)NB_USED * NPH + 64) * 4;
    int* g_cnt = (int*)w;              w += NB * 4;
    int* bucket_base = (int*)w;        w += (NB + 64) * 4;
    int* bucket_cur = (int*)w;

    const int BLK = 256;
    int edge_blocks = (N_EDGES + BLK - 1) / BLK;
    int chunk_blocks = (N_EDGES + 4095) / 4096;

    // --- CSR build (bucket order + per-bucket phase sort) ---
    hipMemsetAsync(g_cnt, 0, NB * sizeof(int), stream);
    bucket_hist_kernel<<<chunk_blocks, 256, 0, stream>>>(row, col, g_cnt);
    bucket_scan_kernel<<<1, NB, 0, stream>>>(g_cnt, bucket_base, bucket_cur);
    bin_kernel<<<chunk_blocks, 1024, 0, stream>>>(row, col, bucket_cur, binned);
    phase_sort_kernel<<<NB_USED, 1024, 0, stream>>>(binned, bucket_base, offs4, entries);

    // --- input network ---
    input_kernel<<<IN_BLOCKS, BLK, 0, stream>>>(x, win_w, win_b, xh0, xs);

    // --- message-passing iterations (ping-pong H table) ---
    uint4* cur = xh0;
    uint4* nxt = xh1;
    for (int it = 0; it < 3; it++) {
        node_kernel<<<NB_USED, 1024, 0, stream>>>(
            cur, xs, offs4, entries, e1_w, e1_b, e2_w, e2_b,
            n1_w, n1_b, n2_w, n2_b, nxt);
        uint4* t = cur; cur = nxt; nxt = t;
    }

    // --- final edge network -> out ---
    edge_kernel<<<edge_blocks, BLK, 0, stream>>>(
        row, col, cur, xs, e1_w, e1_b, e2_w, e2_b, out);
}